// Round 8
// baseline (667.226 us; speedup 1.0000x reference)
//
#include <hip/hip_runtime.h>

#define NN    4096
#define BB    4
#define INDIM 64
#define HD    256
#define KMAX  32
#define SLOTS 33   // K neighbors + self

// ---------------------------------------------------------------------------
// Kernel 1: XL = x@Wl + bl, XR = x@Wr + br   ([16384,64] @ [64,256])
// 256 threads/block, 32 nodes/block. x chunk transposed in LDS (pad 36).
// ---------------------------------------------------------------------------
__global__ __launch_bounds__(256) void xlr_kernel(
    const float* __restrict__ x,
    const float* __restrict__ Wl, const float* __restrict__ bl,
    const float* __restrict__ Wr, const float* __restrict__ br,
    float* __restrict__ XL, float* __restrict__ XR)
{
    __shared__ float xs[INDIM][36];   // [c][m], pad 36: 16B-aligned rows, spread write banks
    const int t = threadIdx.x;        // output column 0..255
    const int base = blockIdx.x * 32; // first node of this chunk

    // load 32x64 x-chunk as float4, store transposed
    #pragma unroll
    for (int r = 0; r < 2; ++r) {
        float4 xv4 = ((const float4*)x)[(size_t)base * (INDIM / 4) + r * 256 + t];
        int l = (r * 256 + t) * 4;
        int m = l >> 6, c = l & 63;
        xs[c + 0][m] = xv4.x;
        xs[c + 1][m] = xv4.y;
        xs[c + 2][m] = xv4.z;
        xs[c + 3][m] = xv4.w;
    }
    __syncthreads();

    float accl[32], accr[32];
    #pragma unroll
    for (int m = 0; m < 32; ++m) { accl[m] = 0.f; accr[m] = 0.f; }

    for (int c = 0; c < INDIM; ++c) {
        float wl = Wl[c * HD + t];
        float wr = Wr[c * HD + t];
        float xv[32];
        const float4* xp = (const float4*)&xs[c][0];   // broadcast reads
        float4* dst = (float4*)xv;
        #pragma unroll
        for (int q = 0; q < 8; ++q) dst[q] = xp[q];
        #pragma unroll
        for (int m = 0; m < 32; ++m) {
            accl[m] = fmaf(xv[m], wl, accl[m]);
            accr[m] = fmaf(xv[m], wr, accr[m]);
        }
    }

    float blv = bl[t], brv = br[t];
    #pragma unroll
    for (int m = 0; m < 32; ++m) {
        XL[(size_t)(base + m) * HD + t] = accl[m] + blv;
        XR[(size_t)(base + m) * HD + t] = accr[m] + brv;
    }
}

// ---------------------------------------------------------------------------
// Kernel 2: per-node fused GATv2 attention + aggregate + bias + LayerNorm.
// One block (256 thr) per node. Wave h == head h (D=64 == wavefront).
// R3 change: gathered neighbor rows staged in LDS (33 KB), NOT in a
// per-thread register array (r2's xlv[33] spilled to scratch: VGPR=32,
// 17% HBM, latency-bound). e-comp + aggregate read xls[k][t]: bank t%32,
// 2-way aliasing = free.
// ---------------------------------------------------------------------------
__global__ __launch_bounds__(256, 4) void gat_kernel(
    const float* __restrict__ adj,
    const float* __restrict__ XL, const float* __restrict__ XR,
    const float* __restrict__ att, const float* __restrict__ bias,
    const float* __restrict__ gamma, const float* __restrict__ beta,
    float* __restrict__ out)
{
    const int node = blockIdx.x;          // b*N + i
    const int b    = node >> 12;          // N = 4096
    const int i    = node & (NN - 1);
    const int t    = threadIdx.x;         // feature index h*64+d
    const int h    = t >> 6;              // head == wave
    const int lane = t & 63;

    __shared__ float xls[SLOTS][HD];      // 33 KB staged neighbor rows
    __shared__ int   s_nbr[SLOTS];
    __shared__ float s_a[4][SLOTS];       // e, then alpha (per-head)
    __shared__ float s_red[4];
    __shared__ int   s_cnt;

    // hoisted independent loads — in flight under the adjacency scan
    const float xr    = XR[(size_t)node * HD + t];
    const float attv  = att[t];           // att is [H,D] flat = 256
    const float biasv = bias[t];
    const float gv    = gamma[t];
    const float bv    = beta[t];

    // ---- Phase A: scan adjacency row (16 KB), compact nonzero columns ----
    const float4* row = (const float4*)(adj + (size_t)node * NN);
    float4 v[4];
    #pragma unroll
    for (int r = 0; r < 4; ++r) v[r] = row[r * 256 + t];

    if (t == 0) s_cnt = 0;
    __syncthreads();

    #pragma unroll
    for (int r = 0; r < 4; ++r) {
        int j0 = (r * 256 + t) * 4;
        if (v[r].x > 0.f) { int p = atomicAdd(&s_cnt, 1); if (p < KMAX) s_nbr[p] = j0;     }
        if (v[r].y > 0.f) { int p = atomicAdd(&s_cnt, 1); if (p < KMAX) s_nbr[p] = j0 + 1; }
        if (v[r].z > 0.f) { int p = atomicAdd(&s_cnt, 1); if (p < KMAX) s_nbr[p] = j0 + 2; }
        if (v[r].w > 0.f) { int p = atomicAdd(&s_cnt, 1); if (p < KMAX) s_nbr[p] = j0 + 3; }
    }
    __syncthreads();
    int cnt = s_cnt; if (cnt > KMAX) cnt = KMAX;
    // fill slot cnt (self-loop) and pad slots [cnt+1..32] with self (alpha=0 later)
    if (t >= cnt && t < SLOTS) s_nbr[t] = i;
    __syncthreads();
    const int total = cnt + 1;            // valid slots: 0..cnt (incl. self)

    const size_t bbase = (size_t)b * NN * HD;

    // ---- Phase B0: stage all neighbor rows into LDS ----
    // wave w handles slots k = w, w+4, ..., issuing ALL loads before writes
    float4 tmp[9];
    #pragma unroll
    for (int ii = 0; ii < 9; ++ii) {
        int k = h + 4 * ii;
        if (k < SLOTS)
            tmp[ii] = ((const float4*)(XL + bbase + (size_t)s_nbr[k] * HD))[lane];
    }
    #pragma unroll
    for (int ii = 0; ii < 9; ++ii) {
        int k = h + 4 * ii;
        if (k < SLOTS)
            ((float4*)&xls[k][0])[lane] = tmp[ii];
    }
    __syncthreads();

    // ---- Phase B2: e_k = att . leaky_relu(xl_k + xr) via wave reduce ----
    #pragma unroll
    for (int k = 0; k < SLOTS; ++k) {
        float s = xls[k][t] + xr;
        s = fmaxf(s, 0.f) + 0.2f * fminf(s, 0.f);   // leaky_relu, branchless
        float c = attv * s;
        #pragma unroll
        for (int off = 32; off; off >>= 1) c += __shfl_xor(c, off);
        if (lane == 0) s_a[h][k] = c;
    }
    __syncthreads();

    // ---- softmax over slots (one wave per head, slots fit in 64 lanes) ----
    float e = (lane < total) ? s_a[h][lane] : -3.0e38f;
    float m = e;
    #pragma unroll
    for (int off = 32; off; off >>= 1) m = fmaxf(m, __shfl_xor(m, off));
    float p = (lane < total) ? __expf(e - m) : 0.f;
    float sm = p;
    #pragma unroll
    for (int off = 32; off; off >>= 1) sm += __shfl_xor(sm, off);
    float alpha = p / sm;                 // 0 for padded slots
    if (lane < SLOTS) s_a[h][lane] = alpha;
    __syncthreads();

    // ---- aggregate from LDS + bias ----
    float acc = 0.f;
    #pragma unroll
    for (int k = 0; k < SLOTS; ++k) acc = fmaf(s_a[h][k], xls[k][t], acc);
    acc += biasv;

    // ---- LayerNorm over 256 features (two-pass, block reduce) ----
    float ssum = acc;
    #pragma unroll
    for (int off = 32; off; off >>= 1) ssum += __shfl_xor(ssum, off);
    if (lane == 0) s_red[h] = ssum;
    __syncthreads();
    float mu = (s_red[0] + s_red[1] + s_red[2] + s_red[3]) * (1.f / 256.f);
    __syncthreads();
    float d  = acc - mu;
    float dv = d * d;
    #pragma unroll
    for (int off = 32; off; off >>= 1) dv += __shfl_xor(dv, off);
    if (lane == 0) s_red[h] = dv;
    __syncthreads();
    float var  = (s_red[0] + s_red[1] + s_red[2] + s_red[3]) * (1.f / 256.f);
    float rstd = rsqrtf(var + 1e-5f);
    out[(size_t)node * HD + t] = d * rstd * gv + bv;
}

// ---------------------------------------------------------------------------
extern "C" void kernel_launch(void* const* d_in, const int* in_sizes, int n_in,
                              void* d_out, int out_size, void* d_ws, size_t ws_size,
                              hipStream_t stream)
{
    const float* x     = (const float*)d_in[0];
    const float* adj   = (const float*)d_in[1];
    const float* Wl    = (const float*)d_in[2];
    const float* bl    = (const float*)d_in[3];
    const float* Wr    = (const float*)d_in[4];
    const float* br    = (const float*)d_in[5];
    const float* att   = (const float*)d_in[6];
    const float* bias  = (const float*)d_in[7];
    const float* gamma = (const float*)d_in[8];
    const float* beta  = (const float*)d_in[9];
    float* out = (float*)d_out;

    float* XL = (float*)d_ws;                       // 16 MiB
    float* XR = XL + (size_t)BB * NN * HD;          // 16 MiB

    xlr_kernel<<<BB * NN / 32, 256, 0, stream>>>(x, Wl, bl, Wr, br, XL, XR);
    gat_kernel<<<BB * NN, 256, 0, stream>>>(adj, XL, XR, att, bias, gamma, beta, out);
}

// Round 10
// 555.906 us; speedup vs baseline: 1.2002x; 1.2002x over previous
//
#include <hip/hip_runtime.h>

#define NN    4096
#define BB    4
#define INDIM 64
#define HD    256
#define KMAX  32
#define SLOTS 33   // K neighbors + self

// ---------------------------------------------------------------------------
// Kernel 1: XL = x@Wl + bl, XR = x@Wr + br   ([16384,64] @ [64,256])
// 256 threads/block, 32 nodes/block. x chunk transposed in LDS.
// R8: __launch_bounds__(256,2) -> 256-VGPR cap (accl/accr = 64 regs live;
// prior default target spilled -> ~285us). Static float4 consumption, no
// reinterpret-cast through a local array (SROA blocker).
// ---------------------------------------------------------------------------
__global__ __launch_bounds__(256, 2) void xlr_kernel(
    const float* __restrict__ x,
    const float* __restrict__ Wl, const float* __restrict__ bl,
    const float* __restrict__ Wr, const float* __restrict__ br,
    float* __restrict__ XL, float* __restrict__ XR)
{
    __shared__ float xs[INDIM][36];   // [c][m], pad 36
    const int t = threadIdx.x;        // output column 0..255
    const int base = blockIdx.x * 32; // first node of this chunk

    // load 32x64 x-chunk as float4, store transposed
    #pragma unroll
    for (int r = 0; r < 2; ++r) {
        float4 xv4 = ((const float4*)x)[(size_t)base * (INDIM / 4) + r * 256 + t];
        int l = (r * 256 + t) * 4;
        int m = l >> 6, c = l & 63;
        xs[c + 0][m] = xv4.x;
        xs[c + 1][m] = xv4.y;
        xs[c + 2][m] = xv4.z;
        xs[c + 3][m] = xv4.w;
    }
    __syncthreads();

    float accl[32], accr[32];
    #pragma unroll
    for (int m = 0; m < 32; ++m) { accl[m] = 0.f; accr[m] = 0.f; }

    for (int c = 0; c < INDIM; ++c) {
        float wl = Wl[c * HD + t];
        float wr = Wr[c * HD + t];
        const float4* xp = (const float4*)&xs[c][0];   // LDS broadcast reads
        #pragma unroll
        for (int q = 0; q < 8; ++q) {
            float4 xq = xp[q];
            accl[4*q+0] = fmaf(xq.x, wl, accl[4*q+0]);
            accl[4*q+1] = fmaf(xq.y, wl, accl[4*q+1]);
            accl[4*q+2] = fmaf(xq.z, wl, accl[4*q+2]);
            accl[4*q+3] = fmaf(xq.w, wl, accl[4*q+3]);
            accr[4*q+0] = fmaf(xq.x, wr, accr[4*q+0]);
            accr[4*q+1] = fmaf(xq.y, wr, accr[4*q+1]);
            accr[4*q+2] = fmaf(xq.z, wr, accr[4*q+2]);
            accr[4*q+3] = fmaf(xq.w, wr, accr[4*q+3]);
        }
    }

    float blv = bl[t], brv = br[t];
    #pragma unroll
    for (int m = 0; m < 32; ++m) {
        XL[(size_t)(base + m) * HD + t] = accl[m] + blv;
        XR[(size_t)(base + m) * HD + t] = accr[m] + brv;
    }
}

// ---------------------------------------------------------------------------
// Kernel 2: per-node fused GATv2 attention + aggregate + bias + LayerNorm.
// One block (256 thr) per node. Wave h == head h (D=64 == wavefront).
// R8: stage neighbor rows via __builtin_amdgcn_global_load_lds (direct
// global->LDS DMA, no VGPR round-trip). R3's reg-staging tmp[9] spilled:
// WRITE_SIZE grew by EXACTLY 2112 float4/block = 540672 KiB. Zero temp
// registers now; __syncthreads() drains vmcnt before xls reads.
// ---------------------------------------------------------------------------
__global__ __launch_bounds__(256, 4) void gat_kernel(
    const float* __restrict__ adj,
    const float* __restrict__ XL, const float* __restrict__ XR,
    const float* __restrict__ att, const float* __restrict__ bias,
    const float* __restrict__ gamma, const float* __restrict__ beta,
    float* __restrict__ out)
{
    const int node = blockIdx.x;          // b*N + i
    const int b    = node >> 12;          // N = 4096
    const int i    = node & (NN - 1);
    const int t    = threadIdx.x;         // feature index h*64+d
    const int h    = t >> 6;              // head == wave
    const int lane = t & 63;

    __shared__ float xls[SLOTS][HD];      // 33 KB staged neighbor rows
    __shared__ int   s_nbr[SLOTS];
    __shared__ float s_a[4][SLOTS];       // e, then alpha (per-head)
    __shared__ float s_red[4];
    __shared__ int   s_cnt;

    // hoisted independent loads — in flight under the adjacency scan
    const float xr    = XR[(size_t)node * HD + t];
    const float attv  = att[t];           // att is [H,D] flat = 256
    const float biasv = bias[t];
    const float gv    = gamma[t];
    const float bv    = beta[t];

    // ---- Phase A: scan adjacency row (16 KB), compact nonzero columns ----
    const float4* row = (const float4*)(adj + (size_t)node * NN);
    float4 v[4];
    #pragma unroll
    for (int r = 0; r < 4; ++r) v[r] = row[r * 256 + t];

    if (t == 0) s_cnt = 0;
    __syncthreads();

    #pragma unroll
    for (int r = 0; r < 4; ++r) {
        int j0 = (r * 256 + t) * 4;
        if (v[r].x > 0.f) { int p = atomicAdd(&s_cnt, 1); if (p < KMAX) s_nbr[p] = j0;     }
        if (v[r].y > 0.f) { int p = atomicAdd(&s_cnt, 1); if (p < KMAX) s_nbr[p] = j0 + 1; }
        if (v[r].z > 0.f) { int p = atomicAdd(&s_cnt, 1); if (p < KMAX) s_nbr[p] = j0 + 2; }
        if (v[r].w > 0.f) { int p = atomicAdd(&s_cnt, 1); if (p < KMAX) s_nbr[p] = j0 + 3; }
    }
    __syncthreads();
    int cnt = s_cnt; if (cnt > KMAX) cnt = KMAX;
    // fill slot cnt (self-loop) and pad slots [cnt+1..32] with self (alpha=0 later)
    if (t >= cnt && t < SLOTS) s_nbr[t] = i;
    __syncthreads();
    const int total = cnt + 1;            // valid slots: 0..cnt (incl. self)

    const size_t bbase = (size_t)b * NN * HD;

    // ---- Phase B0: async-stage neighbor rows global->LDS (no VGPRs) ----
    // wave h handles slots k = h, h+4, ... ; per slot: 64 lanes x 16 B = 1 KB
    // row. LDS dest = wave-uniform base + lane*16 (k uniform per wave);
    // global src = row base + lane*16. Verified semantics (m97/m104).
    #pragma unroll
    for (int ii = 0; ii < 9; ++ii) {
        int k = h + 4 * ii;
        if (k < SLOTS) {
            const float* g = XL + bbase + (size_t)s_nbr[k] * HD + lane * 4;
            __builtin_amdgcn_global_load_lds(
                (const __attribute__((address_space(1))) void*)g,
                (__attribute__((address_space(3))) void*)&xls[k][0],
                16, 0, 0);
        }
    }
    __syncthreads();   // drains vmcnt(0) before any xls read

    // ---- Phase B2: e_k = att . leaky_relu(xl_k + xr) via wave reduce ----
    #pragma unroll
    for (int k = 0; k < SLOTS; ++k) {
        float s = xls[k][t] + xr;
        s = fmaxf(s, 0.f) + 0.2f * fminf(s, 0.f);   // leaky_relu, branchless
        float c = attv * s;
        #pragma unroll
        for (int off = 32; off; off >>= 1) c += __shfl_xor(c, off);
        if (lane == 0) s_a[h][k] = c;
    }
    __syncthreads();

    // ---- softmax over slots (one wave per head, slots fit in 64 lanes) ----
    float e = (lane < total) ? s_a[h][lane] : -3.0e38f;
    float m = e;
    #pragma unroll
    for (int off = 32; off; off >>= 1) m = fmaxf(m, __shfl_xor(m, off));
    float p = (lane < total) ? __expf(e - m) : 0.f;
    float sm = p;
    #pragma unroll
    for (int off = 32; off; off >>= 1) sm += __shfl_xor(sm, off);
    float alpha = p / sm;                 // 0 for padded slots
    if (lane < SLOTS) s_a[h][lane] = alpha;
    __syncthreads();

    // ---- aggregate from LDS + bias ----
    float acc = 0.f;
    #pragma unroll
    for (int k = 0; k < SLOTS; ++k) acc = fmaf(s_a[h][k], xls[k][t], acc);
    acc += biasv;

    // ---- LayerNorm over 256 features (two-pass, block reduce) ----
    float ssum = acc;
    #pragma unroll
    for (int off = 32; off; off >>= 1) ssum += __shfl_xor(ssum, off);
    if (lane == 0) s_red[h] = ssum;
    __syncthreads();
    float mu = (s_red[0] + s_red[1] + s_red[2] + s_red[3]) * (1.f / 256.f);
    __syncthreads();
    float d  = acc - mu;
    float dv = d * d;
    #pragma unroll
    for (int off = 32; off; off >>= 1) dv += __shfl_xor(dv, off);
    if (lane == 0) s_red[h] = dv;
    __syncthreads();
    float var  = (s_red[0] + s_red[1] + s_red[2] + s_red[3]) * (1.f / 256.f);
    float rstd = rsqrtf(var + 1e-5f);
    out[(size_t)node * HD + t] = d * rstd * gv + bv;
}

// ---------------------------------------------------------------------------
extern "C" void kernel_launch(void* const* d_in, const int* in_sizes, int n_in,
                              void* d_out, int out_size, void* d_ws, size_t ws_size,
                              hipStream_t stream)
{
    const float* x     = (const float*)d_in[0];
    const float* adj   = (const float*)d_in[1];
    const float* Wl    = (const float*)d_in[2];
    const float* bl    = (const float*)d_in[3];
    const float* Wr    = (const float*)d_in[4];
    const float* br    = (const float*)d_in[5];
    const float* att   = (const float*)d_in[6];
    const float* bias  = (const float*)d_in[7];
    const float* gamma = (const float*)d_in[8];
    const float* beta  = (const float*)d_in[9];
    float* out = (float*)d_out;

    float* XL = (float*)d_ws;                       // 16 MiB
    float* XR = XL + (size_t)BB * NN * HD;          // 16 MiB

    xlr_kernel<<<BB * NN / 32, 256, 0, stream>>>(x, Wl, bl, Wr, br, XL, XR);
    gat_kernel<<<BB * NN, 256, 0, stream>>>(adj, XL, XR, att, bias, gamma, beta, out);
}

// Round 12
// 418.881 us; speedup vs baseline: 1.5929x; 1.3271x over previous
//
#include <hip/hip_runtime.h>

#define NN    4096
#define BB    4
#define INDIM 64
#define HD    256
#define KMAX  32
#define SLOTS 33   // K neighbors + self

// ---------------------------------------------------------------------------
// Kernel 1: XL = x@Wl + bl, XR = x@Wr + br   ([16384,64] @ [64,256])
// R10: dead-simple 4-nodes-per-block. x rows are block-uniform -> scalar
// (SGPR) loads; W reads coalesced, L1/L2-resident; 8 named accumulators;
// zero LDS, zero barriers. Decides whether the constant ~290us residual
// is xlr or harness overhead.
// ---------------------------------------------------------------------------
__global__ __launch_bounds__(256, 4) void xlr_kernel(
    const float* __restrict__ x,
    const float* __restrict__ Wl, const float* __restrict__ bl,
    const float* __restrict__ Wr, const float* __restrict__ br,
    float* __restrict__ XL, float* __restrict__ XR)
{
    const int t = threadIdx.x;            // output feature 0..255
    const int base = blockIdx.x * 4;      // 4 nodes per block
    const float* xp = x + (size_t)base * INDIM;

    float al0=0.f, al1=0.f, al2=0.f, al3=0.f;
    float ar0=0.f, ar1=0.f, ar2=0.f, ar3=0.f;

    #pragma unroll 8
    for (int c = 0; c < INDIM; ++c) {
        float wl = Wl[c * HD + t];
        float wr = Wr[c * HD + t];
        float x0 = xp[c];                 // uniform -> s_load
        float x1 = xp[INDIM + c];
        float x2 = xp[2 * INDIM + c];
        float x3 = xp[3 * INDIM + c];
        al0 = fmaf(x0, wl, al0); ar0 = fmaf(x0, wr, ar0);
        al1 = fmaf(x1, wl, al1); ar1 = fmaf(x1, wr, ar1);
        al2 = fmaf(x2, wl, al2); ar2 = fmaf(x2, wr, ar2);
        al3 = fmaf(x3, wl, al3); ar3 = fmaf(x3, wr, ar3);
    }
    const float blv = bl[t], brv = br[t];
    XL[(size_t)(base + 0) * HD + t] = al0 + blv;
    XL[(size_t)(base + 1) * HD + t] = al1 + blv;
    XL[(size_t)(base + 2) * HD + t] = al2 + blv;
    XL[(size_t)(base + 3) * HD + t] = al3 + blv;
    XR[(size_t)(base + 0) * HD + t] = ar0 + brv;
    XR[(size_t)(base + 1) * HD + t] = ar1 + brv;
    XR[(size_t)(base + 2) * HD + t] = ar2 + brv;
    XR[(size_t)(base + 3) * HD + t] = ar3 + brv;
}

// ---------------------------------------------------------------------------
// Kernel 2: fused GATv2 + bias + LayerNorm, one block per node.
// R10 rewrite: single online-softmax pass. Lane l owns features 4l..4l+3
// (head = l/16). Per slot: 1 coalesced float4 row load from L2 (no LDS
// staging), 16-lane butterfly (4 shfl, not 6), pure-VALU online update.
// Waves split slots 4-way; (m,s,acc) merged via 6KB LDS. DS-pipe ops/block
// ~1200 -> ~320 (R10 counters: VALUBusy 26%, HBM 14%, conflicts 0 ->
// LDS-pipe serialization was the bottleneck).
// ---------------------------------------------------------------------------
__global__ __launch_bounds__(256, 4) void gat_kernel(
    const float* __restrict__ adj,
    const float* __restrict__ XL, const float* __restrict__ XR,
    const float* __restrict__ att, const float* __restrict__ bias,
    const float* __restrict__ gamma, const float* __restrict__ beta,
    float* __restrict__ out)
{
    const int node = blockIdx.x;          // b*N + i
    const int b    = node >> 12;          // N = 4096
    const int i    = node & (NN - 1);
    const int t    = threadIdx.x;
    const int w    = t >> 6;              // wave id
    const int l    = t & 63;              // lane

    __shared__ int   s_nbr[SLOTS];
    __shared__ int   s_cnt;
    __shared__ float s_acc[4][HD];        // per-wave weighted sums (feature-major)
    __shared__ float s_m[4][64];          // per-wave running max (per lane)
    __shared__ float s_s[4][64];          // per-wave running denom
    __shared__ float s_red[4];

    // 4-feature view for the online pass (features 4l..4l+3, head l/16)
    const float4 xr4  = *(const float4*)(XR + (size_t)node * HD + 4 * l);
    const float4 att4 = *(const float4*)(att + 4 * l);
    // feature-t view for merge/LN
    const float biasv = bias[t];
    const float gv    = gamma[t];
    const float bv    = beta[t];

    // ---- Phase A: scan adjacency row (16 KB), compact nonzero columns ----
    const float4* row = (const float4*)(adj + (size_t)node * NN);
    float4 v[4];
    #pragma unroll
    for (int r = 0; r < 4; ++r) v[r] = row[r * 256 + t];

    if (t == 0) s_cnt = 0;
    __syncthreads();

    #pragma unroll
    for (int r = 0; r < 4; ++r) {
        int j0 = (r * 256 + t) * 4;
        if (v[r].x > 0.f) { int p = atomicAdd(&s_cnt, 1); if (p < KMAX) s_nbr[p] = j0;     }
        if (v[r].y > 0.f) { int p = atomicAdd(&s_cnt, 1); if (p < KMAX) s_nbr[p] = j0 + 1; }
        if (v[r].z > 0.f) { int p = atomicAdd(&s_cnt, 1); if (p < KMAX) s_nbr[p] = j0 + 2; }
        if (v[r].w > 0.f) { int p = atomicAdd(&s_cnt, 1); if (p < KMAX) s_nbr[p] = j0 + 3; }
    }
    __syncthreads();
    int cnt = s_cnt; if (cnt > KMAX) cnt = KMAX;
    if (t >= cnt && t < SLOTS) s_nbr[t] = i;      // self-loop at slot cnt
    __syncthreads();
    const int total = cnt + 1;                    // valid slots 0..cnt

    const size_t bbase = (size_t)b * NN * HD;

    // ---- fused online-softmax pass: wave w handles slots w, w+4, ... ----
    float m = -3.0e38f, s = 0.f;
    float a0 = 0.f, a1 = 0.f, a2 = 0.f, a3 = 0.f;
    for (int k = w; k < total; k += 4) {
        int j = s_nbr[k];                          // wave-uniform broadcast
        float4 q = *(const float4*)(XL + bbase + (size_t)j * HD + 4 * l);
        float s0 = q.x + xr4.x; s0 = fmaxf(s0, 0.f) + 0.2f * fminf(s0, 0.f);
        float s1 = q.y + xr4.y; s1 = fmaxf(s1, 0.f) + 0.2f * fminf(s1, 0.f);
        float s2 = q.z + xr4.z; s2 = fmaxf(s2, 0.f) + 0.2f * fminf(s2, 0.f);
        float s3 = q.w + xr4.w; s3 = fmaxf(s3, 0.f) + 0.2f * fminf(s3, 0.f);
        float c = att4.x * s0;
        c = fmaf(att4.y, s1, c);
        c = fmaf(att4.z, s2, c);
        c = fmaf(att4.w, s3, c);
        // 16-lane butterfly: reduces over d within head (masks stay in group)
        c += __shfl_xor(c, 1);
        c += __shfl_xor(c, 2);
        c += __shfl_xor(c, 4);
        c += __shfl_xor(c, 8);
        // online softmax update (pure VALU)
        float mn    = fmaxf(m, c);
        float scale = __expf(m - mn);              // 0 on first iteration
        float p     = __expf(c - mn);
        s  = s * scale + p;
        a0 = fmaf(p, q.x, a0 * scale);
        a1 = fmaf(p, q.y, a1 * scale);
        a2 = fmaf(p, q.z, a2 * scale);
        a3 = fmaf(p, q.w, a3 * scale);
        m  = mn;
    }
    // publish per-wave state
    *(float4*)&s_acc[w][4 * l] = make_float4(a0, a1, a2, a3);
    s_m[w][l] = m;
    s_s[w][l] = s;
    __syncthreads();

    // ---- merge 4 waves (thread t <-> feature t; holder lane g = t/4) ----
    const int g = t >> 2;
    float m0 = s_m[0][g], m1 = s_m[1][g], m2 = s_m[2][g], m3 = s_m[3][g];
    float M  = fmaxf(fmaxf(m0, m1), fmaxf(m2, m3));
    float w0 = __expf(m0 - M), w1 = __expf(m1 - M);
    float w2 = __expf(m2 - M), w3 = __expf(m3 - M);
    float den = w0 * s_s[0][g] + w1 * s_s[1][g] + w2 * s_s[2][g] + w3 * s_s[3][g];
    float num = w0 * s_acc[0][t] + w1 * s_acc[1][t] + w2 * s_acc[2][t] + w3 * s_acc[3][t];
    float acc = num / den + biasv;

    // ---- LayerNorm over 256 features (two-pass, block reduce) ----
    float ssum = acc;
    #pragma unroll
    for (int off = 32; off; off >>= 1) ssum += __shfl_xor(ssum, off);
    if (l == 0) s_red[w] = ssum;
    __syncthreads();
    float mu = (s_red[0] + s_red[1] + s_red[2] + s_red[3]) * (1.f / 256.f);
    __syncthreads();
    float d  = acc - mu;
    float dv = d * d;
    #pragma unroll
    for (int off = 32; off; off >>= 1) dv += __shfl_xor(dv, off);
    if (l == 0) s_red[w] = dv;
    __syncthreads();
    float var  = (s_red[0] + s_red[1] + s_red[2] + s_red[3]) * (1.f / 256.f);
    float rstd = rsqrtf(var + 1e-5f);
    out[(size_t)node * HD + t] = d * rstd * gv + bv;
}

// ---------------------------------------------------------------------------
extern "C" void kernel_launch(void* const* d_in, const int* in_sizes, int n_in,
                              void* d_out, int out_size, void* d_ws, size_t ws_size,
                              hipStream_t stream)
{
    const float* x     = (const float*)d_in[0];
    const float* adj   = (const float*)d_in[1];
    const float* Wl    = (const float*)d_in[2];
    const float* bl    = (const float*)d_in[3];
    const float* Wr    = (const float*)d_in[4];
    const float* br    = (const float*)d_in[5];
    const float* att   = (const float*)d_in[6];
    const float* bias  = (const float*)d_in[7];
    const float* gamma = (const float*)d_in[8];
    const float* beta  = (const float*)d_in[9];
    float* out = (float*)d_out;

    float* XL = (float*)d_ws;                       // 16 MiB
    float* XR = XL + (size_t)BB * NN * HD;          // 16 MiB

    xlr_kernel<<<BB * NN / 4, 256, 0, stream>>>(x, Wl, bl, Wr, br, XL, XR);
    gat_kernel<<<BB * NN, 256, 0, stream>>>(adj, XL, XR, att, bias, gamma, beta, out);
}